// Round 2
// baseline (661.070 us; speedup 1.0000x reference)
//
#include <hip/hip_runtime.h>

#define NN 100000     // nodes
#define NE 1600000    // edges
#define D  64         // feature dim (in == out)

// ---- workspace layout (ints) ----
// deg    : [0, NN)            per-dst degree
// rowptr : [NN, 2*NN)         exclusive prefix sum of deg
// cursor : [2*NN, 3*NN)       fill cursor; post-fill cursor[i] == rowptr[i+1]
// nbr    : [3*NN, 3*NN+NE)    CSR adjacency (src indices grouped by dst)
// total 7.6 MB << ws_size (round 1 used 25.6 MB successfully)

__global__ void zero_deg(int* __restrict__ deg) {
    int i = blockIdx.x * blockDim.x + threadIdx.x;
    if (i < NN) deg[i] = 0;
}

__global__ void hist_kernel(const int* __restrict__ ei, int* __restrict__ deg) {
    int e = blockIdx.x * blockDim.x + threadIdx.x;
    if (e < NE) atomicAdd(&deg[ei[NE + e]], 1);   // dst row of edge_index
}

// Single-block exclusive scan of deg[0..NN) -> rowptr, cursor.
__global__ __launch_bounds__(1024) void scan_kernel(const int* __restrict__ deg,
                                                    int* __restrict__ rowptr,
                                                    int* __restrict__ cursor) {
    __shared__ int tmp[1024];
    const int t  = threadIdx.x;
    const int CH = (NN + 1023) / 1024;   // 98 elements per thread
    const int base = t * CH;
    int s = 0;
    for (int j = 0; j < CH; ++j) {
        int i = base + j;
        if (i < NN) s += deg[i];
    }
    tmp[t] = s;
    __syncthreads();
    for (int off = 1; off < 1024; off <<= 1) {   // Hillis-Steele inclusive scan
        int v = (t >= off) ? tmp[t - off] : 0;
        __syncthreads();
        tmp[t] += v;
        __syncthreads();
    }
    int run = tmp[t] - s;                        // exclusive prefix at chunk start
    for (int j = 0; j < CH; ++j) {
        int i = base + j;
        if (i < NN) {
            rowptr[i] = run;
            cursor[i] = run;
            run += deg[i];
        }
    }
}

__global__ void fill_kernel(const int* __restrict__ ei,
                            int* __restrict__ cursor,
                            int* __restrict__ nbr) {
    int e = blockIdx.x * blockDim.x + threadIdx.x;
    if (e < NE) {
        int src = ei[e];
        int dst = ei[NE + e];
        int pos = atomicAdd(&cursor[dst], 1);
        nbr[pos] = src;
    }
}

// One wave per node (grid-stride): h[node] = (1+eps)*x[node] + sum_j x[nbr[j]].
// Row loads are 256B coalesced; 4-deep manual pipeline for outstanding loads.
// Low VGPR count -> high occupancy to hide gather latency. Writes into d_out.
__global__ void gather_kernel(const float* __restrict__ x,
                              const float* __restrict__ eps,
                              const int* __restrict__ rowptr,
                              const int* __restrict__ rowend,   // = post-fill cursor
                              const int* __restrict__ nbr,
                              float* __restrict__ h) {
    const int lane   = threadIdx.x & 63;
    const int wave   = blockIdx.x * (blockDim.x >> 6) + (threadIdx.x >> 6);
    const int nwaves = gridDim.x * (blockDim.x >> 6);
    const float e1 = 1.0f + *eps;

    for (int node = wave; node < NN; node += nwaves) {
        const int r0 = rowptr[node];
        const int r1 = rowend[node];
        float acc = e1 * x[node * D + lane];
        int p = r0;
        for (; p + 4 <= r1; p += 4) {
            int i0 = nbr[p], i1 = nbr[p + 1], i2 = nbr[p + 2], i3 = nbr[p + 3];
            float v0 = x[i0 * D + lane];
            float v1 = x[i1 * D + lane];
            float v2 = x[i2 * D + lane];
            float v3 = x[i3 * D + lane];
            acc += (v0 + v1) + (v2 + v3);
        }
        for (; p < r1; ++p) acc += x[nbr[p] * D + lane];
        h[node * D + lane] = acc;
    }
}

// In-place MLP on d_out: out[node] = relu(h[node]@W1+b1)@W2+b2.
// Lane d holds column d of W1/W2 in registers; h[k] broadcast via v_readlane.
__global__ __launch_bounds__(256) void mlp_kernel(float* __restrict__ h,
                                                  const float* __restrict__ W1,
                                                  const float* __restrict__ b1,
                                                  const float* __restrict__ W2,
                                                  const float* __restrict__ b2) {
    const int lane   = threadIdx.x & 63;
    const int wave   = blockIdx.x * (blockDim.x >> 6) + (threadIdx.x >> 6);
    const int nwaves = gridDim.x * (blockDim.x >> 6);

    float w1[D], w2[D];
    #pragma unroll
    for (int k = 0; k < D; ++k) {
        w1[k] = W1[k * D + lane];
        w2[k] = W2[k * D + lane];
    }
    const float bb1 = b1[lane];
    const float bb2 = b2[lane];

    for (int node = wave; node < NN; node += nwaves) {
        float hv = h[node * D + lane];
        float acc1 = bb1;
        #pragma unroll
        for (int k = 0; k < D; ++k) {
            float s = __int_as_float(__builtin_amdgcn_readlane(__float_as_int(hv), k));
            acc1 = fmaf(s, w1[k], acc1);
        }
        acc1 = fmaxf(acc1, 0.0f);
        float acc2 = bb2;
        #pragma unroll
        for (int k = 0; k < D; ++k) {
            float s = __int_as_float(__builtin_amdgcn_readlane(__float_as_int(acc1), k));
            acc2 = fmaf(s, w2[k], acc2);
        }
        h[node * D + lane] = acc2;   // in-place: same wave read this row above
    }
}

extern "C" void kernel_launch(void* const* d_in, const int* in_sizes, int n_in,
                              void* d_out, int out_size, void* d_ws, size_t ws_size,
                              hipStream_t stream) {
    const float* x   = (const float*)d_in[0];
    const int*   ei  = (const int*)d_in[1];
    const float* W1  = (const float*)d_in[2];
    const float* b1  = (const float*)d_in[3];
    const float* W2  = (const float*)d_in[4];
    const float* b2  = (const float*)d_in[5];
    const float* eps = (const float*)d_in[6];
    float*       out = (float*)d_out;

    int* deg    = (int*)d_ws;
    int* rowptr = deg + NN;
    int* cursor = rowptr + NN;
    int* nbr    = cursor + NN;

    zero_deg<<<(NN + 255) / 256, 256, 0, stream>>>(deg);
    hist_kernel<<<(NE + 255) / 256, 256, 0, stream>>>(ei, deg);
    scan_kernel<<<1, 1024, 0, stream>>>(deg, rowptr, cursor);
    fill_kernel<<<(NE + 255) / 256, 256, 0, stream>>>(ei, cursor, nbr);

    // gather writes h0 into d_out; mlp transforms d_out in place
    gather_kernel<<<2048, 256, 0, stream>>>(x, eps, rowptr, cursor, nbr, out);
    mlp_kernel<<<1024, 256, 0, stream>>>(out, W1, b1, W2, b2);
}

// Round 3
// 408.041 us; speedup vs baseline: 1.6201x; 1.6201x over previous
//
#include <hip/hip_runtime.h>

#define NN 100000     // nodes
#define NE 1600000    // edges
#define D  64         // feature dim (in == out)
#define NB 98         // ceil(NN / 1024) — scan blocks

// ---- workspace layout (ints) ----
// deg    : [0, NN)
// rowptr : [NN, 2*NN)
// cursor : [2*NN, 3*NN)          post-fill cursor[i] == rowptr[i+1]
// nbr    : [3*NN, 3*NN+NE)
// bsum   : [3*NN+NE, +NB)
// boff   : [.., +NB)

__global__ void zero_deg(int* __restrict__ deg) {
    int i = blockIdx.x * blockDim.x + threadIdx.x;
    if (i < NN) deg[i] = 0;
}

__global__ void hist_kernel(const int* __restrict__ ei, int* __restrict__ deg) {
    int e = blockIdx.x * blockDim.x + threadIdx.x;
    if (e < NE) atomicAdd(&deg[ei[NE + e]], 1);   // dst row
}

// Phase A: block b sums deg[b*1024 .. b*1024+1024) -> bsum[b]. Coalesced.
__global__ __launch_bounds__(256) void scanA(const int* __restrict__ deg,
                                             int* __restrict__ bsum) {
    const int b = blockIdx.x, t = threadIdx.x;
    const int base = b * 1024;
    int s = 0;
    #pragma unroll
    for (int j = 0; j < 4; ++j) {
        int i = base + t + j * 256;
        if (i < NN) s += deg[i];
    }
    #pragma unroll
    for (int off = 32; off; off >>= 1) s += __shfl_down(s, off, 64);
    __shared__ int ws[4];
    if ((t & 63) == 0) ws[t >> 6] = s;
    __syncthreads();
    if (t == 0) bsum[b] = ws[0] + ws[1] + ws[2] + ws[3];
}

// Phase B: single small block scans NB partials -> exclusive boff.
__global__ __launch_bounds__(128) void scanB(const int* __restrict__ bsum,
                                             int* __restrict__ boff) {
    __shared__ int tmp[128];
    const int t = threadIdx.x;
    int v = (t < NB) ? bsum[t] : 0;
    tmp[t] = v;
    __syncthreads();
    for (int off = 1; off < 128; off <<= 1) {
        int u = (t >= off) ? tmp[t - off] : 0;
        __syncthreads();
        tmp[t] += u;
        __syncthreads();
    }
    if (t < NB) boff[t] = tmp[t] - v;   // exclusive
}

// Phase C: block-local exclusive scan (int4 per thread) + block offset.
__global__ __launch_bounds__(256) void scanC(const int* __restrict__ deg,
                                             const int* __restrict__ boff,
                                             int* __restrict__ rowptr,
                                             int* __restrict__ cursor) {
    __shared__ int tmp[256];
    const int b = blockIdx.x, t = threadIdx.x;
    const int i0 = b * 1024 + t * 4;
    int d0 = 0, d1 = 0, d2 = 0, d3 = 0;
    if (i0 + 3 < NN) {
        int4 v = *(const int4*)(deg + i0);
        d0 = v.x; d1 = v.y; d2 = v.z; d3 = v.w;
    } else {
        if (i0     < NN) d0 = deg[i0];
        if (i0 + 1 < NN) d1 = deg[i0 + 1];
        if (i0 + 2 < NN) d2 = deg[i0 + 2];
        if (i0 + 3 < NN) d3 = deg[i0 + 3];
    }
    const int s = d0 + d1 + d2 + d3;
    tmp[t] = s;
    __syncthreads();
    for (int off = 1; off < 256; off <<= 1) {
        int u = (t >= off) ? tmp[t - off] : 0;
        __syncthreads();
        tmp[t] += u;
        __syncthreads();
    }
    int r0 = boff[b] + tmp[t] - s;      // exclusive prefix of element i0
    int r1 = r0 + d0, r2 = r1 + d1, r3 = r2 + d2;
    if (i0 + 3 < NN) {
        *(int4*)(rowptr + i0) = make_int4(r0, r1, r2, r3);
        *(int4*)(cursor + i0) = make_int4(r0, r1, r2, r3);
    } else {
        if (i0     < NN) { rowptr[i0]     = r0; cursor[i0]     = r0; }
        if (i0 + 1 < NN) { rowptr[i0 + 1] = r1; cursor[i0 + 1] = r1; }
        if (i0 + 2 < NN) { rowptr[i0 + 2] = r2; cursor[i0 + 2] = r2; }
        if (i0 + 3 < NN) { rowptr[i0 + 3] = r3; cursor[i0 + 3] = r3; }
    }
}

__global__ void fill_kernel(const int* __restrict__ ei,
                            int* __restrict__ cursor,
                            int* __restrict__ nbr) {
    int e = blockIdx.x * blockDim.x + threadIdx.x;
    if (e < NE) {
        int src = ei[e];
        int dst = ei[NE + e];
        int pos = atomicAdd(&cursor[dst], 1);
        nbr[pos] = src;
    }
}

// One wave per node: h[node] = (1+eps)*x[node] + sum_j x[nbr[j]]. Writes d_out.
__global__ void gather_kernel(const float* __restrict__ x,
                              const float* __restrict__ eps,
                              const int* __restrict__ rowptr,
                              const int* __restrict__ rowend,   // post-fill cursor
                              const int* __restrict__ nbr,
                              float* __restrict__ h) {
    const int lane   = threadIdx.x & 63;
    const int wave   = blockIdx.x * (blockDim.x >> 6) + (threadIdx.x >> 6);
    const int nwaves = gridDim.x * (blockDim.x >> 6);
    const float e1 = 1.0f + *eps;

    for (int node = wave; node < NN; node += nwaves) {
        const int r0 = rowptr[node];
        const int r1 = rowend[node];
        float acc = e1 * x[node * D + lane];
        int p = r0;
        for (; p + 4 <= r1; p += 4) {
            int i0 = nbr[p], i1 = nbr[p + 1], i2 = nbr[p + 2], i3 = nbr[p + 3];
            float v0 = x[i0 * D + lane];
            float v1 = x[i1 * D + lane];
            float v2 = x[i2 * D + lane];
            float v3 = x[i3 * D + lane];
            acc += (v0 + v1) + (v2 + v3);
        }
        for (; p < r1; ++p) acc += x[nbr[p] * D + lane];
        h[node * D + lane] = acc;
    }
}

// In-place MLP on d_out: out = relu(h@W1+b1)@W2+b2. Weights in registers,
// h[k] broadcast via v_readlane.
__global__ __launch_bounds__(256) void mlp_kernel(float* __restrict__ h,
                                                  const float* __restrict__ W1,
                                                  const float* __restrict__ b1,
                                                  const float* __restrict__ W2,
                                                  const float* __restrict__ b2) {
    const int lane   = threadIdx.x & 63;
    const int wave   = blockIdx.x * (blockDim.x >> 6) + (threadIdx.x >> 6);
    const int nwaves = gridDim.x * (blockDim.x >> 6);

    float w1[D], w2[D];
    #pragma unroll
    for (int k = 0; k < D; ++k) {
        w1[k] = W1[k * D + lane];
        w2[k] = W2[k * D + lane];
    }
    const float bb1 = b1[lane];
    const float bb2 = b2[lane];

    for (int node = wave; node < NN; node += nwaves) {
        float hv = h[node * D + lane];
        float acc1 = bb1;
        #pragma unroll
        for (int k = 0; k < D; ++k) {
            float s = __int_as_float(__builtin_amdgcn_readlane(__float_as_int(hv), k));
            acc1 = fmaf(s, w1[k], acc1);
        }
        acc1 = fmaxf(acc1, 0.0f);
        float acc2 = bb2;
        #pragma unroll
        for (int k = 0; k < D; ++k) {
            float s = __int_as_float(__builtin_amdgcn_readlane(__float_as_int(acc1), k));
            acc2 = fmaf(s, w2[k], acc2);
        }
        h[node * D + lane] = acc2;
    }
}

extern "C" void kernel_launch(void* const* d_in, const int* in_sizes, int n_in,
                              void* d_out, int out_size, void* d_ws, size_t ws_size,
                              hipStream_t stream) {
    const float* x   = (const float*)d_in[0];
    const int*   ei  = (const int*)d_in[1];
    const float* W1  = (const float*)d_in[2];
    const float* b1  = (const float*)d_in[3];
    const float* W2  = (const float*)d_in[4];
    const float* b2  = (const float*)d_in[5];
    const float* eps = (const float*)d_in[6];
    float*       out = (float*)d_out;

    int* deg    = (int*)d_ws;
    int* rowptr = deg + NN;
    int* cursor = rowptr + NN;
    int* nbr    = cursor + NN;
    int* bsum   = nbr + NE;
    int* boff   = bsum + NB;

    zero_deg<<<(NN + 255) / 256, 256, 0, stream>>>(deg);
    hist_kernel<<<(NE + 255) / 256, 256, 0, stream>>>(ei, deg);
    scanA<<<NB, 256, 0, stream>>>(deg, bsum);
    scanB<<<1, 128, 0, stream>>>(bsum, boff);
    scanC<<<NB, 256, 0, stream>>>(deg, boff, rowptr, cursor);
    fill_kernel<<<(NE + 255) / 256, 256, 0, stream>>>(ei, cursor, nbr);

    gather_kernel<<<2048, 256, 0, stream>>>(x, eps, rowptr, cursor, nbr, out);
    mlp_kernel<<<1024, 256, 0, stream>>>(out, W1, b1, W2, b2);
}